// Round 5
// baseline (182.848 us; speedup 1.0000x reference)
//
#include <hip/hip_runtime.h>

// mean(|box5(x)-box5(y)|) = mean(|box5(x-y)|); separable 5x5 box, pad=4.
// B=64, H=W=512, out 516x516.
// R5: defeat the allocator's load-sinking. (1) __launch_bounds__(256,2)
// gives a ~256-VGPR budget (R2-R4's bare (256) made the allocator minimize
// pressure and serialize all loads: VGPR 44/72/84, MLP~0.3). (2) No hist[]
// registers: subtract row r-5 by RELOADING it (L1/L2 hit). (3) 4-row burst
// iterations: 16-32 independent float4 loads issued before one consume
// point, pinned with a single sched_barrier(0).
// Wave = (img, 12-row band); 64*43 = 2752 waves = 688 blocks.

#define TRB     12
#define NBANDS  43                    // 43*12 = 516
#define NBLOCKS ((NBANDS * 64) / 4)   // 688

__global__ __launch_bounds__(256, 2) void box_loss_kernel(
    const float* __restrict__ x, const float* __restrict__ y,
    float* __restrict__ ws, float* __restrict__ out)
{
    __shared__ float wsum[4];

    const int lane = threadIdx.x & 63;
    const int wid  = (blockIdx.x << 2) + (threadIdx.x >> 6);
    const int img  = wid / NBANDS;
    const int band = wid - img * NBANDS;
    const int i0   = band * TRB;            // first output row

    const size_t base = (size_t)img * (512 * 512) + (size_t)(lane * 8);
    const float* xb = x + base;
    const float* yb = y + base;

    float v[8];
    #pragma unroll
    for (int j = 0; j < 8; ++j) v[j] = 0.f;
    float acc = 0.f;

    // ---- warm-up burst: rows i0-4 .. i0-1 (fresh only, 16 independent loads)
    {
        float4 fx[4][2], fy[4][2];
        #pragma unroll
        for (int j = 0; j < 4; ++j) {
            const int r  = i0 - 4 + j;
            const int rc = max(r, 0);            // r <= 503, no high clamp
            const float4* xr = (const float4*)(xb + (size_t)rc * 512);
            const float4* yr = (const float4*)(yb + (size_t)rc * 512);
            fx[j][0] = xr[0]; fx[j][1] = xr[1];
            fy[j][0] = yr[0]; fy[j][1] = yr[1];
        }
        __builtin_amdgcn_sched_barrier(0);
        #pragma unroll
        for (int j = 0; j < 4; ++j) {
            const bool val = (i0 - 4 + j) >= 0;
            float dm[8];
            dm[0] = fx[j][0].x - fy[j][0].x; dm[1] = fx[j][0].y - fy[j][0].y;
            dm[2] = fx[j][0].z - fy[j][0].z; dm[3] = fx[j][0].w - fy[j][0].w;
            dm[4] = fx[j][1].x - fy[j][1].x; dm[5] = fx[j][1].y - fy[j][1].y;
            dm[6] = fx[j][1].z - fy[j][1].z; dm[7] = fx[j][1].w - fy[j][1].w;
            #pragma unroll
            for (int k = 0; k < 8; ++k) v[k] += val ? dm[k] : 0.f;
        }
    }

    // ---- main: 3 iterations x 4 rows; each burst = 32 independent loads
    #pragma unroll
    for (int it = 0; it < 3; ++it) {
        const int r0 = i0 + it * 4;
        float4 fx[4][2], fy[4][2], ox[4][2], oy[4][2];
        #pragma unroll
        for (int j = 0; j < 4; ++j) {
            const int r   = r0 + j;              // i0 .. i0+11 (<= 515)
            const int rc  = min(r, 511);
            const int ro  = r - 5;               // i0-5 .. i0+6
            const int roc = max(ro, 0);          // <= 510
            const float4* xr = (const float4*)(xb + (size_t)rc * 512);
            const float4* yr = (const float4*)(yb + (size_t)rc * 512);
            const float4* xo = (const float4*)(xb + (size_t)roc * 512);
            const float4* yo = (const float4*)(yb + (size_t)roc * 512);
            fx[j][0] = xr[0]; fx[j][1] = xr[1];
            fy[j][0] = yr[0]; fy[j][1] = yr[1];
            ox[j][0] = xo[0]; ox[j][1] = xo[1];
            oy[j][0] = yo[0]; oy[j][1] = yo[1];
        }
        __builtin_amdgcn_sched_barrier(0);
        #pragma unroll
        for (int j = 0; j < 4; ++j) {
            const int r = r0 + j;
            const bool val  = (r < 512);
            // subtract row r-5 only if it was added (r >= i0+1) and real (r-5 >= 0)
            const bool sval = (r - 5 >= 0) & (r - 5 >= i0 - 4);
            float dm[8], dq[8];
            dm[0] = fx[j][0].x - fy[j][0].x; dm[1] = fx[j][0].y - fy[j][0].y;
            dm[2] = fx[j][0].z - fy[j][0].z; dm[3] = fx[j][0].w - fy[j][0].w;
            dm[4] = fx[j][1].x - fy[j][1].x; dm[5] = fx[j][1].y - fy[j][1].y;
            dm[6] = fx[j][1].z - fy[j][1].z; dm[7] = fx[j][1].w - fy[j][1].w;
            dq[0] = ox[j][0].x - oy[j][0].x; dq[1] = ox[j][0].y - oy[j][0].y;
            dq[2] = ox[j][0].z - oy[j][0].z; dq[3] = ox[j][0].w - oy[j][0].w;
            dq[4] = ox[j][1].x - oy[j][1].x; dq[5] = ox[j][1].y - oy[j][1].y;
            dq[6] = ox[j][1].z - oy[j][1].z; dq[7] = ox[j][1].w - oy[j][1].w;
            #pragma unroll
            for (int k = 0; k < 8; ++k) {
                v[k] += (val ? dm[k] : 0.f) - (sval ? dq[k] : 0.f);
            }

            // horizontal 5-tap: halo = prev lane's v[4..7]
            float h0 = __shfl_up(v[4], 1, 64);
            float h1 = __shfl_up(v[5], 1, 64);
            float h2 = __shfl_up(v[6], 1, 64);
            float h3 = __shfl_up(v[7], 1, 64);
            if (lane == 0) { h0 = 0.f; h1 = 0.f; h2 = 0.f; h3 = 0.f; }

            float s = h0 + h1 + h2 + h3 + v[0];   // out col c0
            acc += fabsf(s);
            s += v[1] - h0;   acc += fabsf(s);
            s += v[2] - h1;   acc += fabsf(s);
            s += v[3] - h2;   acc += fabsf(s);
            s += v[4] - h3;   acc += fabsf(s);
            s += v[5] - v[0]; acc += fabsf(s);
            s += v[6] - v[1]; acc += fabsf(s);
            s += v[7] - v[2]; acc += fabsf(s);
            if (lane == 63) {                     // out cols 512..515
                float q = v[7];  acc += fabsf(q);
                q += v[6];       acc += fabsf(q);
                q += v[5];       acc += fabsf(q);
                q += v[4];       acc += fabsf(q);
            }
        }
    }

    // ---- wave reduce, block reduce, global atomic, fused finalize
    #pragma unroll
    for (int off = 32; off > 0; off >>= 1)
        acc += __shfl_down(acc, off, 64);
    if (lane == 0) wsum[threadIdx.x >> 6] = acc;
    __syncthreads();

    if (threadIdx.x == 0) {
        float s = wsum[0] + wsum[1] + wsum[2] + wsum[3];
        atomicAdd(ws, s);
        __threadfence();
        unsigned* cnt = (unsigned*)(ws + 1);
        unsigned done = atomicAdd(cnt, 1u);
        if (done == (unsigned)(gridDim.x - 1)) {
            float total = atomicAdd(ws, 0.0f);    // coherent read of final sum
            out[0] = total * (1.0f / (25.0f * 64.0f * 516.0f * 516.0f));
        }
    }
}

extern "C" void kernel_launch(void* const* d_in, const int* in_sizes, int n_in,
                              void* d_out, int out_size, void* d_ws, size_t ws_size,
                              hipStream_t stream) {
    const float* x = (const float*)d_in[0];
    const float* y = (const float*)d_in[1];
    float* out = (float*)d_out;
    float* ws  = (float*)d_ws;

    hipMemsetAsync(ws, 0, 8, stream);   // ws[0]=sum, ws[1]=block counter

    box_loss_kernel<<<NBLOCKS, 256, 0, stream>>>(x, y, ws, out);
}